// Round 9
// baseline (264.651 us; speedup 1.0000x reference)
//
#include <hip/hip_runtime.h>

#define DCH 128
#define ROWS 16
#define BN_EPS 1e-5f

typedef unsigned short u16;
typedef __attribute__((ext_vector_type(8))) short short8;
typedef __attribute__((ext_vector_type(4))) float floatx4;

__device__ __forceinline__ float bf2f(u16 u) {
    return __uint_as_float(((unsigned)u) << 16);
}
__device__ __forceinline__ u16 f2bf(float f) {
    unsigned u = __float_as_uint(f);
    u += 0x7FFFu + ((u >> 16) & 1u);   // RNE, finite inputs
    return (u16)(u >> 16);
}
__device__ __forceinline__ float ldf(const void* p, int i, int isbf) {
    return isbf ? bf2f(((const u16*)p)[i]) : ((const float*)p)[i];
}

// ws_i[0]=edge-is-int64  ws_i[1]=floats-are-bf16  ws_i[2]=errbits
// block 0: detect flags then pack W (B-frag order); blocks 1..: zero deg/sums/sumsq
__global__ void prep_kernel(const int* ei, int ewords, const u16* xw, int* ws_i,
                            const void* W, u16* Wb, float* zbase, int zn) {
    int t = threadIdx.x;
    if (blockIdx.x == 0) {
        __shared__ int s_nz, s_hits;
        if (t == 0) { s_nz = 0; s_hits = 0; }
        __syncthreads();
        int nz = 0;
        for (int i = t; i < 1024; i += 256) {
            int w = 2 * i + 1;
            if (w < ewords) nz |= ei[w];
        }
        if (nz) atomicOr(&s_nz, 1);
        unsigned m = (xw[2 * t] >> 8) & 0x7F;
        if (m >= 0x3B && m <= 0x43) atomicAdd(&s_hits, 1);
        __syncthreads();
        int isbf = (s_hits >= 128) ? 1 : 0;
        if (t == 0) {
            ws_i[0] = (s_nz == 0) ? 1 : 0;
            ws_i[1] = isbf;
            ws_i[2] = 0;
        }
        // pack W: Wb[((nt*4+kk)*64+lane)*8+j] = bf16(W[(kk*32+(lane>>4)*8+j)*128 + nt*16+(lane&15)])
        for (int idx = t; idx < DCH * DCH; idx += 256) {
            int j = idx & 7, lane = (idx >> 3) & 63, kk = (idx >> 9) & 3, nt = idx >> 11;
            int k = kk * 32 + (lane >> 4) * 8 + j;
            int n = nt * 16 + (lane & 15);
            Wb[idx] = f2bf(ldf(W, k * DCH + n, isbf));
        }
    } else {
        int stride = (gridDim.x - 1) * 256;
        for (int i = (blockIdx.x - 1) * 256 + t; i < zn; i += stride) zbase[i] = 0.f;
    }
}

__global__ void zero_kernel(float* p, int n) {
    int stride = gridDim.x * 256;
    for (int i = blockIdx.x * 256 + threadIdx.x; i < n; i += stride) p[i] = 0.f;
}

__global__ void paint_kernel(u16* out, int n, unsigned val) {
    int stride = gridDim.x * 256;
    for (int i = blockIdx.x * 256 + threadIdx.x; i < n; i += stride) out[i] = (u16)val;
}

__global__ void detect_kernel(const int* ei, int ewords, const u16* xw, int* ws_i) {
    __shared__ int s_nz, s_hits;
    int t = threadIdx.x;
    if (t == 0) { s_nz = 0; s_hits = 0; }
    __syncthreads();
    int nz = 0;
    for (int i = t; i < 1024; i += 256) {
        int w = 2 * i + 1;
        if (w < ewords) nz |= ei[w];
    }
    if (nz) atomicOr(&s_nz, 1);
    unsigned m = (xw[2 * t] >> 8) & 0x7F;
    if (m >= 0x3B && m <= 0x43) atomicAdd(&s_hits, 1);
    __syncthreads();
    if (t == 0) {
        ws_i[0] = (s_nz == 0) ? 1 : 0;
        ws_i[1] = (s_hits >= 128) ? 1 : 0;
        ws_i[2] = 0;
    }
}

__global__ void deg_kernel(const int* ei, int E, int* ws_i, int* deg, int N) {
    int is64 = ws_i[0];
    int i = blockIdx.x * 256 + threadIdx.x;
    if (i < E) {
        int s = is64 ? ei[2 * i] : ei[i];
        int d = is64 ? ei[2 * E + 2 * i] : ei[E + i];
        if (((unsigned)s >= (unsigned)N) || ((unsigned)d >= (unsigned)N))
            atomicOr(&ws_i[2], 2);
        d = min(max(d, 0), N - 1);
        atomicAdd(&deg[d], 1);
    }
}

__global__ void dinv_kernel(const int* deg, float* dinv, int N, int* ws_i) {
    int i = blockIdx.x * 256 + threadIdx.x;
    if (i < N) {
        float v = rsqrtf((float)(deg[i] + 1));
        if (!(v > 0.f && v <= 1.001f)) atomicOr(&ws_i[2], 4);
        dinv[i] = v;
    }
}

// ---- 3-phase exclusive scan of deg -> rowptr, in-place cursor; dinv fused in C ----
__global__ void scanA_kernel(const int* deg, int* part, int N) {
    int base = blockIdx.x * 1024 + threadIdx.x * 4;
    int s = 0;
    #pragma unroll
    for (int j = 0; j < 4; ++j) {
        int i = base + j;
        if (i < N) s += deg[i];
    }
    #pragma unroll
    for (int o = 1; o < 64; o <<= 1) s += __shfl_xor(s, o, 64);
    __shared__ int ws4[4];
    if ((threadIdx.x & 63) == 0) ws4[threadIdx.x >> 6] = s;
    __syncthreads();
    if (threadIdx.x == 0) part[blockIdx.x] = ws4[0] + ws4[1] + ws4[2] + ws4[3];
}

__global__ void scanB_kernel(int* part, int P) {   // P <= 256
    __shared__ int wsum[4];
    int t = threadIdx.x, lane = t & 63, w = t >> 6;
    int v = (t < P) ? part[t] : 0;
    int sc = v;
    #pragma unroll
    for (int o = 1; o < 64; o <<= 1) {
        int u = __shfl_up(sc, o, 64);
        if (lane >= o) sc += u;
    }
    if (lane == 63) wsum[w] = sc;
    __syncthreads();
    if (t < 4) {
        int s = wsum[t];
        #pragma unroll
        for (int o = 1; o < 4; o <<= 1) {
            int u = __shfl_up(s, o, 4);
            if (t >= o) s += u;
        }
        wsum[t] = s;
    }
    __syncthreads();
    int excl = sc - v + (w ? wsum[w - 1] : 0);
    if (t < P) part[t] = excl;
}

__global__ void scanC_kernel(int* deg_cursor, const int* part, int* rowptr,
                             float* dinv, int N) {
    __shared__ int wsum[4];
    int t = threadIdx.x, lane = t & 63, w = t >> 6;
    int base = blockIdx.x * 1024 + t * 4;
    int v[4], ts = 0;
    #pragma unroll
    for (int j = 0; j < 4; ++j) {
        int i = base + j;
        v[j] = (i < N) ? deg_cursor[i] : 0;
        ts += v[j];
    }
    int sc = ts;
    #pragma unroll
    for (int o = 1; o < 64; o <<= 1) {
        int u = __shfl_up(sc, o, 64);
        if (lane >= o) sc += u;
    }
    if (lane == 63) wsum[w] = sc;
    __syncthreads();
    if (t < 4) {
        int s = wsum[t];
        #pragma unroll
        for (int o = 1; o < 4; o <<= 1) {
            int u = __shfl_up(s, o, 4);
            if (t >= o) s += u;
        }
        wsum[t] = s;
    }
    __syncthreads();
    int run = sc - ts + (w ? wsum[w - 1] : 0) + part[blockIdx.x];
    #pragma unroll
    for (int j = 0; j < 4; ++j) {
        int i = base + j;
        if (i < N) {
            deg_cursor[i] = run;                       // exclusive (cursor start)
            run += v[j];
            rowptr[i + 1] = run;                       // inclusive
            dinv[i] = rsqrtf((float)(v[j] + 1));       // fused dinv
        }
    }
    if (blockIdx.x == 0 && t == 0) rowptr[0] = 0;
}
// ------------------------------------------------------------------

__global__ void fillcsr_kernel(const int* ei, int E, const int* ws_i,
                               int* cursor, int* col, int N) {
    int is64 = ws_i[0];
    int i = blockIdx.x * 256 + threadIdx.x;
    if (i < E) {
        int s = is64 ? ei[2 * i] : ei[i];
        int d = is64 ? ei[2 * E + 2 * i] : ei[E + i];
        s = min(max(s, 0), N - 1);
        d = min(max(d, 0), N - 1);
        int pos = atomicAdd(&cursor[d], 1);
        col[pos] = s;
    }
}

// LDS-free MFMA GEMM: A-frags straight from x, B-frags from prepacked Wb.
__global__ void gemm_mfma_kernel(const void* x, const u16* Wb, const float* dinv,
                                 const int* ws_i, u16* y, int N) {
    int isbf = ws_i[1];
    int t = threadIdx.x;
    int wv = t >> 6, lane = t & 63;
    int quad = lane >> 4, l16 = lane & 15;
    int r0 = blockIdx.x * 64 + wv * 16;
    int rl = min(r0 + l16, N - 1);
    short8 a[4];
    if (isbf) {
        const u16* xp = (const u16*)x + (size_t)rl * DCH + quad * 8;
        #pragma unroll
        for (int kk = 0; kk < 4; ++kk)
            a[kk] = *(const short8*)(xp + kk * 32);
    } else {
        const float* xp = (const float*)x + (size_t)rl * DCH + quad * 8;
        #pragma unroll
        for (int kk = 0; kk < 4; ++kk) {
            float4 f0 = *(const float4*)(xp + kk * 32);
            float4 f1 = *(const float4*)(xp + kk * 32 + 4);
            short8 aa;
            aa[0] = (short)f2bf(f0.x); aa[1] = (short)f2bf(f0.y);
            aa[2] = (short)f2bf(f0.z); aa[3] = (short)f2bf(f0.w);
            aa[4] = (short)f2bf(f1.x); aa[5] = (short)f2bf(f1.y);
            aa[6] = (short)f2bf(f1.z); aa[7] = (short)f2bf(f1.w);
            a[kk] = aa;
        }
    }
    floatx4 acc[8];
    #pragma unroll
    for (int i = 0; i < 8; ++i) acc[i] = (floatx4)(0.f);
    #pragma unroll
    for (int nt = 0; nt < 8; ++nt) {
        #pragma unroll
        for (int kk = 0; kk < 4; ++kk) {
            short8 bfr = *(const short8*)&Wb[(((nt << 2) | kk) * 64 + lane) * 8];
            acc[nt] = __builtin_amdgcn_mfma_f32_16x16x32_bf16(a[kk], bfr, acc[nt], 0, 0, 0);
        }
    }
    #pragma unroll
    for (int i = 0; i < 4; ++i) {
        int row = r0 + quad * 4 + i;
        if (row < N) {
            float dv = dinv[row];
            #pragma unroll
            for (int nt = 0; nt < 8; ++nt)
                y[(size_t)row * DCH + nt * 16 + l16] = f2bf(acc[nt][i] * dv);
        }
    }
}

// gather + BN-stats fused. Lane l: edge-slot g=l>>4, channel-group cl=l&15 (8 ch).
// 16B uint4 loads (8 bf16), 4 edges per wave-iteration, shfl_xor combine.
__global__ void gather_stats_kernel(const int* rowptr, const int* col, const u16* y,
                                    const float* dinv, const void* b, const int* ws_i,
                                    float* h, float* sums, float* sumsq, int N) {
    int isbf = ws_i[1];
    int t = threadIdx.x;
    int w = t >> 6, lane = t & 63;
    int g = lane >> 4, cl = lane & 15;
    int c0 = cl * 8;
    float bb[8];
    #pragma unroll
    for (int k = 0; k < 8; ++k) bb[k] = ldf(b, c0 + k, isbf);
    float ps[8], pq[8];
    #pragma unroll
    for (int k = 0; k < 8; ++k) { ps[k] = 0.f; pq[k] = 0.f; }
    int wid = blockIdx.x * 4 + w;
    int nw = gridDim.x * 4;
    for (int n = wid; n < N; n += nw) {
        float acc[8];
        if (g == 0) {
            uint4 q = *(const uint4*)&y[(size_t)n * DCH + c0];
            acc[0] = bf2f((u16)(q.x & 0xFFFF)); acc[1] = bf2f((u16)(q.x >> 16));
            acc[2] = bf2f((u16)(q.y & 0xFFFF)); acc[3] = bf2f((u16)(q.y >> 16));
            acc[4] = bf2f((u16)(q.z & 0xFFFF)); acc[5] = bf2f((u16)(q.z >> 16));
            acc[6] = bf2f((u16)(q.w & 0xFFFF)); acc[7] = bf2f((u16)(q.w >> 16));
        } else {
            #pragma unroll
            for (int k = 0; k < 8; ++k) acc[k] = 0.f;
        }
        int beg = rowptr[n], end = rowptr[n + 1];
        for (int j = beg + g; j < end; j += 4) {
            int s = col[j];
            uint4 q = *(const uint4*)&y[(size_t)s * DCH + c0];
            acc[0] += bf2f((u16)(q.x & 0xFFFF)); acc[1] += bf2f((u16)(q.x >> 16));
            acc[2] += bf2f((u16)(q.y & 0xFFFF)); acc[3] += bf2f((u16)(q.y >> 16));
            acc[4] += bf2f((u16)(q.z & 0xFFFF)); acc[5] += bf2f((u16)(q.z >> 16));
            acc[6] += bf2f((u16)(q.w & 0xFFFF)); acc[7] += bf2f((u16)(q.w >> 16));
        }
        #pragma unroll
        for (int k = 0; k < 8; ++k) {
            acc[k] += __shfl_xor(acc[k], 16, 64);
            acc[k] += __shfl_xor(acc[k], 32, 64);
        }
        if (g == 0) {
            float dn = dinv[n];
            float4 o0, o1;
            o0.x = fmaf(acc[0], dn, bb[0]); o0.y = fmaf(acc[1], dn, bb[1]);
            o0.z = fmaf(acc[2], dn, bb[2]); o0.w = fmaf(acc[3], dn, bb[3]);
            o1.x = fmaf(acc[4], dn, bb[4]); o1.y = fmaf(acc[5], dn, bb[5]);
            o1.z = fmaf(acc[6], dn, bb[6]); o1.w = fmaf(acc[7], dn, bb[7]);
            float* hp = &h[(size_t)n * DCH + c0];
            *(float4*)hp = o0;
            *(float4*)(hp + 4) = o1;
            ps[0] += o0.x; pq[0] += o0.x * o0.x;
            ps[1] += o0.y; pq[1] += o0.y * o0.y;
            ps[2] += o0.z; pq[2] += o0.z * o0.z;
            ps[3] += o0.w; pq[3] += o0.w * o0.w;
            ps[4] += o1.x; pq[4] += o1.x * o1.x;
            ps[5] += o1.y; pq[5] += o1.y * o1.y;
            ps[6] += o1.z; pq[6] += o1.z * o1.z;
            ps[7] += o1.w; pq[7] += o1.w * o1.w;
        }
    }
    __shared__ float lps[4][DCH], lpq[4][DCH];
    if (g == 0) {
        #pragma unroll
        for (int k = 0; k < 8; ++k) { lps[w][c0 + k] = ps[k]; lpq[w][c0 + k] = pq[k]; }
    }
    __syncthreads();
    if (t < DCH) {
        float s = (lps[0][t] + lps[1][t]) + (lps[2][t] + lps[3][t]);
        float q = (lpq[0][t] + lpq[1][t]) + (lpq[2][t] + lpq[3][t]);
        atomicAdd(&sums[t], s);
        atomicAdd(&sumsq[t], q);
    }
}

// ---------- fallback (R5-proven) atomic-path kernels ----------
__global__ void gemm_valu_kernel(const void* x, const void* W, const float* dinv,
                                 const int* ws_i, void* y, int N) {
    __shared__ float WsF[64 * DCH];
    __shared__ float xs[ROWS * DCH];
    int isbf = ws_i[1];
    int t = threadIdx.x;
    int r0 = blockIdx.x * ROWS;
    for (int i = t; i < ROWS * DCH; i += 256) {
        int r = r0 + (i >> 7);
        xs[i] = (r < N) ? ldf(x, r * DCH + (i & 127), isbf) : 0.f;
    }
    int d = t & 127, rh = t >> 7;
    float s[8];
    #pragma unroll
    for (int j = 0; j < 8; ++j) s[j] = 0.f;
    for (int half = 0; half < 2; ++half) {
        __syncthreads();
        for (int i = t; i < 64 * DCH; i += 256)
            WsF[i] = ldf(W, half * 64 * DCH + i, isbf);
        __syncthreads();
        #pragma unroll
        for (int j = 0; j < 8; ++j) {
            int rr = rh + 2 * j;
            float a = s[j];
            #pragma unroll 16
            for (int k = 0; k < 64; ++k)
                a = fmaf(xs[rr * DCH + half * 64 + k], WsF[k * DCH + d], a);
            s[j] = a;
        }
    }
    #pragma unroll
    for (int j = 0; j < 8; ++j) {
        int r = r0 + rh + 2 * j;
        if (r < N) {
            float v = s[j] * dinv[r];
            if (isbf) ((u16*)y)[r * DCH + d] = f2bf(v);
            else      ((float*)y)[r * DCH + d] = v;
        }
    }
}

__global__ void scatter_kernel(const int* ei, int E, const int* ws_i,
                               const void* y, float* acc, int N) {
    int is64 = ws_i[0], isbf = ws_i[1];
    int gid = blockIdx.x * 256 + threadIdx.x;
    int e = gid >> 5;
    if (e >= E) return;
    int c0 = (gid & 31) * 4;
    int s = is64 ? ei[2 * e] : ei[e];
    int d = is64 ? ei[2 * E + 2 * e] : ei[E + e];
    s = min(max(s, 0), N - 1);
    d = min(max(d, 0), N - 1);
    float v0, v1, v2, v3;
    if (isbf) {
        uint2 raw = *(const uint2*)&((const u16*)y)[s * DCH + c0];
        v0 = bf2f((u16)(raw.x & 0xFFFF)); v1 = bf2f((u16)(raw.x >> 16));
        v2 = bf2f((u16)(raw.y & 0xFFFF)); v3 = bf2f((u16)(raw.y >> 16));
    } else {
        float4 raw = *(const float4*)&((const float*)y)[s * DCH + c0];
        v0 = raw.x; v1 = raw.y; v2 = raw.z; v3 = raw.w;
    }
    float* a = &acc[d * DCH + c0];
    atomicAdd(a + 0, v0);
    atomicAdd(a + 1, v1);
    atomicAdd(a + 2, v2);
    atomicAdd(a + 3, v3);
}

__global__ void bnstat_kernel(const void* y, float* acc, const float* dinv,
                              const void* b, int* ws_i,
                              float* sums, float* sumsq, int total) {
    int isbf = ws_i[1];
    int t = threadIdx.x;
    int d = t & 127;
    float bb = ldf(b, d, isbf);
    float ps = 0.f, pq = 0.f;
    int stride = gridDim.x * 256;
    for (int i = blockIdx.x * 256 + t; i < total; i += stride) {
        int r = i >> 7;
        float yv = isbf ? bf2f(((const u16*)y)[i]) : ((const float*)y)[i];
        float v = (yv + acc[i]) * dinv[r] + bb;
        acc[i] = v;
        ps += v;
        pq += v * v;
    }
    __shared__ float ls[256], lq[256];
    ls[t] = ps; lq[t] = pq;
    __syncthreads();
    if (t < 128) {
        atomicAdd(&sums[d], ls[t] + ls[t + 128]);
        atomicAdd(&sumsq[d], lq[t] + lq[t + 128]);
    }
}
// --------------------------------------------------------------

__global__ void out_kernel(const float* h, const void* x,
                           const void* gamma, const void* beta,
                           int* ws_i, const float* sums, const float* sumsq,
                           void* out, int total, float invN) {
    __shared__ float sc[DCH], sh[DCH];
    int isbf = ws_i[1];
    int t = threadIdx.x;
    if (t < DCH) {
        float mean = sums[t] * invN;
        float var = fmaxf(sumsq[t] * invN - mean * mean, 0.f);
        float s = ldf(gamma, t, isbf) * rsqrtf(var + BN_EPS);
        if (!(var < 1e8f && fabsf(s) < 1e6f)) atomicOr(&ws_i[2], 32);
        sc[t] = s;
        sh[t] = ldf(beta, t, isbf) - mean * s;
    }
    __syncthreads();
    int stride = gridDim.x * 256;
    if (isbf) {
        for (int i = blockIdx.x * 256 + t; i < total; i += stride) {
            int d = i & 127;
            float v = fmaf(h[i], sc[d], sh[d]);
            v = fmaxf(v, 0.f) + bf2f(((const u16*)x)[i]);
            ((u16*)out)[i] = f2bf(v);
        }
    } else {
        for (int i = blockIdx.x * 256 + t; i < total; i += stride) {
            int d = i & 127;
            float v = fmaf(h[i], sc[d], sh[d]);
            v = fmaxf(v, 0.f) + ((const float*)x)[i];
            ((float*)out)[i] = v;
        }
    }
}

__global__ void diag_kernel(const int* ws_i, void* out, int n) {
    int e = ws_i[2];
    if (!e) return;
    int isbf = ws_i[1];
    float v = 4096.f + 32.f * (float)(e & 63);
    int stride = gridDim.x * 256;
    if (isbf) {
        u16 code = f2bf(v);
        for (int i = blockIdx.x * 256 + threadIdx.x; i < n; i += stride)
            ((u16*)out)[i] = code;
    } else {
        for (int i = blockIdx.x * 256 + threadIdx.x; i < n; i += stride)
            ((float*)out)[i] = v;
    }
}

extern "C" void kernel_launch(void* const* d_in, const int* in_sizes, int n_in,
                              void* d_out, int out_size, void* d_ws, size_t ws_size,
                              hipStream_t stream) {
    const void* x     = d_in[0];
    const void* W     = d_in[1];
    const void* b     = d_in[2];
    const void* gamma = d_in[3];
    const void* beta  = d_in[4];
    const int*  ei    = (const int*)d_in[5];

    const int N  = in_sizes[0] / DCH;   // 50000
    const int E  = in_sizes[5] / 2;     // 640000
    const int ND = N * DCH;             // 6,400,000
    const int P  = (N + 1023) / 1024;   // scan partials (49)

    char* wsb = (char*)d_ws;
    int*  ws_i = (int*)wsb;

    // layout: ws_i 64B | Wb 32KB | deg[N] | sums[128] | sumsq[128] | rowptr[N+1] | dinv[N] | part[256] | h[ND] | col[E]
    size_t o_wb   = 64;
    size_t o_deg  = o_wb + 32768;
    size_t o_sum  = o_deg + 4 * (size_t)N;
    size_t o_sq   = o_sum + 512;
    size_t o_rp   = o_sq + 512;
    size_t o_dinv = o_rp + 4 * ((size_t)N + 1) + 4;
    size_t o_part = o_dinv + 4 * (size_t)N;
    size_t o_h    = (o_part + 1024 + 255) & ~(size_t)255;
    size_t o_col  = o_h + 4 * (size_t)ND;
    size_t need_csr = o_col + 4 * (size_t)E;

    (void)hipGetLastError();

    if (ws_size >= need_csr) {
        u16*   Wb    = (u16*)(wsb + o_wb);
        int*   deg   = (int*)(wsb + o_deg);
        float* sums  = (float*)(wsb + o_sum);
        float* sumsq = (float*)(wsb + o_sq);
        int*   rowptr= (int*)(wsb + o_rp);
        float* dinv  = (float*)(wsb + o_dinv);
        int*   part  = (int*)(wsb + o_part);
        float* h     = (float*)(wsb + o_h);
        int*   col   = (int*)(wsb + o_col);
        u16*   y     = (u16*)d_out;   // bf16 y in d_out until out_kernel overwrites

        prep_kernel<<<65, 256, 0, stream>>>(ei, 2 * E, (const u16*)x, ws_i,
                                            W, Wb, (float*)(wsb + o_deg), N + 256);
        deg_kernel<<<(E + 255) / 256, 256, 0, stream>>>(ei, E, ws_i, deg, N);
        scanA_kernel<<<P, 256, 0, stream>>>(deg, part, N);
        scanB_kernel<<<1, 256, 0, stream>>>(part, P);
        scanC_kernel<<<P, 256, 0, stream>>>(deg, part, rowptr, dinv, N);
        fillcsr_kernel<<<(E + 255) / 256, 256, 0, stream>>>(ei, E, ws_i, deg, col, N);
        gemm_mfma_kernel<<<(N + 63) / 64, 256, 0, stream>>>(x, Wb, dinv, ws_i, y, N);
        gather_stats_kernel<<<1024, 256, 0, stream>>>(rowptr, col, y, dinv, b, ws_i,
                                                      h, sums, sumsq, N);
        out_kernel<<<1024, 256, 0, stream>>>(h, x, gamma, beta, ws_i, sums, sumsq,
                                             d_out, ND, 1.0f / (float)N);
        diag_kernel<<<512, 256, 0, stream>>>(ws_i, d_out, out_size);
    } else {
        // R5-proven fallback: ws_i | deg | dinv | sums | sumsq | acc
        int*   deg   = (int*)(wsb + 16);
        float* dinv  = (float*)(wsb + 16 + 4 * (size_t)N);
        float* sums  = (float*)(wsb + 16 + 8 * (size_t)N);
        float* sumsq = sums + DCH;
        float* acc   = sumsq + DCH;
        size_t need = 16 + 8 * (size_t)N + 1024 + 4 * (size_t)ND;
        if (ws_size < need) {
            int mb = (int)(ws_size >> 20); if (mb > 127) mb = 127;
            float v = 2048.f + 16.f * (float)mb;
            unsigned u; __builtin_memcpy(&u, &v, 4);
            paint_kernel<<<1024, 256, 0, stream>>>((u16*)d_out, out_size, u >> 16);
            return;
        }
        detect_kernel<<<1, 256, 0, stream>>>(ei, 2 * E, (const u16*)x, ws_i);
        zero_kernel<<<2048, 256, 0, stream>>>((float*)(wsb + 16), 2 * N + 256 + ND);
        deg_kernel<<<(E + 255) / 256, 256, 0, stream>>>(ei, E, ws_i, deg, N);
        dinv_kernel<<<(N + 255) / 256, 256, 0, stream>>>(deg, dinv, N, ws_i);
        gemm_valu_kernel<<<(N + ROWS - 1) / ROWS, 256, 0, stream>>>(x, W, dinv, ws_i, d_out, N);
        scatter_kernel<<<(E * 32 + 255) / 256, 256, 0, stream>>>(ei, E, ws_i, d_out, acc, N);
        bnstat_kernel<<<240, 256, 0, stream>>>(d_out, acc, dinv, b, ws_i, sums, sumsq, ND);
        out_kernel<<<256, 256, 0, stream>>>(acc, x, gamma, beta, ws_i, sums, sumsq,
                                            d_out, ND, 1.0f / (float)N);
        diag_kernel<<<512, 256, 0, stream>>>(ws_i, d_out, out_size);
    }

    if (hipGetLastError() != hipSuccess)
        hipMemsetAsync(d_out, 0x42, (size_t)out_size * 2, stream);
}

// Round 10
// 251.708 us; speedup vs baseline: 1.0514x; 1.0514x over previous
//
#include <hip/hip_runtime.h>

#define DCH 128
#define ROWS 16
#define BN_EPS 1e-5f

typedef unsigned short u16;
typedef __attribute__((ext_vector_type(8))) short short8;
typedef __attribute__((ext_vector_type(4))) float floatx4;

__device__ __forceinline__ float bf2f(u16 u) {
    return __uint_as_float(((unsigned)u) << 16);
}
__device__ __forceinline__ u16 f2bf(float f) {
    unsigned u = __float_as_uint(f);
    u += 0x7FFFu + ((u >> 16) & 1u);   // RNE, finite inputs
    return (u16)(u >> 16);
}
__device__ __forceinline__ float ldf(const void* p, int i, int isbf) {
    return isbf ? bf2f(((const u16*)p)[i]) : ((const float*)p)[i];
}

// ws_i[0]=edge-is-int64  ws_i[1]=floats-are-bf16  ws_i[2]=errbits
// block 0: detect flags then pack W (B-frag order); blocks 1..: zero deg/sums/sumsq
__global__ void prep_kernel(const int* ei, int ewords, const u16* xw, int* ws_i,
                            const void* W, u16* Wb, float* zbase, int zn) {
    int t = threadIdx.x;
    if (blockIdx.x == 0) {
        __shared__ int s_nz, s_hits;
        if (t == 0) { s_nz = 0; s_hits = 0; }
        __syncthreads();
        int nz = 0;
        for (int i = t; i < 1024; i += 256) {
            int w = 2 * i + 1;
            if (w < ewords) nz |= ei[w];
        }
        if (nz) atomicOr(&s_nz, 1);
        unsigned m = (xw[2 * t] >> 8) & 0x7F;
        if (m >= 0x3B && m <= 0x43) atomicAdd(&s_hits, 1);
        __syncthreads();
        int isbf = (s_hits >= 128) ? 1 : 0;
        if (t == 0) {
            ws_i[0] = (s_nz == 0) ? 1 : 0;
            ws_i[1] = isbf;
            ws_i[2] = 0;
        }
        // pack W: Wb[((nt*4+kk)*64+lane)*8+j] = bf16(W[(kk*32+(lane>>4)*8+j)*128 + nt*16+(lane&15)])
        for (int idx = t; idx < DCH * DCH; idx += 256) {
            int j = idx & 7, lane = (idx >> 3) & 63, kk = (idx >> 9) & 3, nt = idx >> 11;
            int k = kk * 32 + (lane >> 4) * 8 + j;
            int n = nt * 16 + (lane & 15);
            Wb[idx] = f2bf(ldf(W, k * DCH + n, isbf));
        }
    } else {
        int stride = (gridDim.x - 1) * 256;
        for (int i = (blockIdx.x - 1) * 256 + t; i < zn; i += stride) zbase[i] = 0.f;
    }
}

__global__ void zero_kernel(float* p, int n) {
    int stride = gridDim.x * 256;
    for (int i = blockIdx.x * 256 + threadIdx.x; i < n; i += stride) p[i] = 0.f;
}

__global__ void paint_kernel(u16* out, int n, unsigned val) {
    int stride = gridDim.x * 256;
    for (int i = blockIdx.x * 256 + threadIdx.x; i < n; i += stride) out[i] = (u16)val;
}

__global__ void detect_kernel(const int* ei, int ewords, const u16* xw, int* ws_i) {
    __shared__ int s_nz, s_hits;
    int t = threadIdx.x;
    if (t == 0) { s_nz = 0; s_hits = 0; }
    __syncthreads();
    int nz = 0;
    for (int i = t; i < 1024; i += 256) {
        int w = 2 * i + 1;
        if (w < ewords) nz |= ei[w];
    }
    if (nz) atomicOr(&s_nz, 1);
    unsigned m = (xw[2 * t] >> 8) & 0x7F;
    if (m >= 0x3B && m <= 0x43) atomicAdd(&s_hits, 1);
    __syncthreads();
    if (t == 0) {
        ws_i[0] = (s_nz == 0) ? 1 : 0;
        ws_i[1] = (s_hits >= 128) ? 1 : 0;
        ws_i[2] = 0;
    }
}

__global__ void deg_kernel(const int* ei, int E, int* ws_i, int* deg, int N) {
    int is64 = ws_i[0];
    int i = blockIdx.x * 256 + threadIdx.x;
    if (i < E) {
        int s = is64 ? ei[2 * i] : ei[i];
        int d = is64 ? ei[2 * E + 2 * i] : ei[E + i];
        if (((unsigned)s >= (unsigned)N) || ((unsigned)d >= (unsigned)N))
            atomicOr(&ws_i[2], 2);
        d = min(max(d, 0), N - 1);
        atomicAdd(&deg[d], 1);
    }
}

__global__ void dinv_kernel(const int* deg, float* dinv, int N, int* ws_i) {
    int i = blockIdx.x * 256 + threadIdx.x;
    if (i < N) {
        float v = rsqrtf((float)(deg[i] + 1));
        if (!(v > 0.f && v <= 1.001f)) atomicOr(&ws_i[2], 4);
        dinv[i] = v;
    }
}

// ---- 3-phase exclusive scan of deg -> rowptr, in-place cursor; dinv fused in C ----
__global__ void scanA_kernel(const int* deg, int* part, int N) {
    int base = blockIdx.x * 1024 + threadIdx.x * 4;
    int s = 0;
    #pragma unroll
    for (int j = 0; j < 4; ++j) {
        int i = base + j;
        if (i < N) s += deg[i];
    }
    #pragma unroll
    for (int o = 1; o < 64; o <<= 1) s += __shfl_xor(s, o, 64);
    __shared__ int ws4[4];
    if ((threadIdx.x & 63) == 0) ws4[threadIdx.x >> 6] = s;
    __syncthreads();
    if (threadIdx.x == 0) part[blockIdx.x] = ws4[0] + ws4[1] + ws4[2] + ws4[3];
}

__global__ void scanB_kernel(int* part, int P) {   // P <= 256
    __shared__ int wsum[4];
    int t = threadIdx.x, lane = t & 63, w = t >> 6;
    int v = (t < P) ? part[t] : 0;
    int sc = v;
    #pragma unroll
    for (int o = 1; o < 64; o <<= 1) {
        int u = __shfl_up(sc, o, 64);
        if (lane >= o) sc += u;
    }
    if (lane == 63) wsum[w] = sc;
    __syncthreads();
    if (t < 4) {
        int s = wsum[t];
        #pragma unroll
        for (int o = 1; o < 4; o <<= 1) {
            int u = __shfl_up(s, o, 4);
            if (t >= o) s += u;
        }
        wsum[t] = s;
    }
    __syncthreads();
    int excl = sc - v + (w ? wsum[w - 1] : 0);
    if (t < P) part[t] = excl;
}

__global__ void scanC_kernel(int* deg_cursor, const int* part, int* rowptr,
                             float* dinv, int N) {
    __shared__ int wsum[4];
    int t = threadIdx.x, lane = t & 63, w = t >> 6;
    int base = blockIdx.x * 1024 + t * 4;
    int v[4], ts = 0;
    #pragma unroll
    for (int j = 0; j < 4; ++j) {
        int i = base + j;
        v[j] = (i < N) ? deg_cursor[i] : 0;
        ts += v[j];
    }
    int sc = ts;
    #pragma unroll
    for (int o = 1; o < 64; o <<= 1) {
        int u = __shfl_up(sc, o, 64);
        if (lane >= o) sc += u;
    }
    if (lane == 63) wsum[w] = sc;
    __syncthreads();
    if (t < 4) {
        int s = wsum[t];
        #pragma unroll
        for (int o = 1; o < 4; o <<= 1) {
            int u = __shfl_up(s, o, 4);
            if (t >= o) s += u;
        }
        wsum[t] = s;
    }
    __syncthreads();
    int run = sc - ts + (w ? wsum[w - 1] : 0) + part[blockIdx.x];
    #pragma unroll
    for (int j = 0; j < 4; ++j) {
        int i = base + j;
        if (i < N) {
            deg_cursor[i] = run;                       // exclusive (cursor start)
            run += v[j];
            rowptr[i + 1] = run;                       // inclusive
            dinv[i] = rsqrtf((float)(v[j] + 1));       // fused dinv
        }
    }
    if (blockIdx.x == 0 && t == 0) rowptr[0] = 0;
}
// ------------------------------------------------------------------

__global__ void fillcsr_kernel(const int* ei, int E, const int* ws_i,
                               int* cursor, int* col, int N) {
    int is64 = ws_i[0];
    int i = blockIdx.x * 256 + threadIdx.x;
    if (i < E) {
        int s = is64 ? ei[2 * i] : ei[i];
        int d = is64 ? ei[2 * E + 2 * i] : ei[E + i];
        s = min(max(s, 0), N - 1);
        d = min(max(d, 0), N - 1);
        int pos = atomicAdd(&cursor[d], 1);
        col[pos] = s;
    }
}

// LDS-free MFMA GEMM: A-frags straight from x, B-frags from prepacked Wb.
__global__ void gemm_mfma_kernel(const void* x, const u16* Wb, const float* dinv,
                                 const int* ws_i, u16* y, int N) {
    int isbf = ws_i[1];
    int t = threadIdx.x;
    int wv = t >> 6, lane = t & 63;
    int quad = lane >> 4, l16 = lane & 15;
    int r0 = blockIdx.x * 64 + wv * 16;
    int rl = min(r0 + l16, N - 1);
    short8 a[4];
    if (isbf) {
        const u16* xp = (const u16*)x + (size_t)rl * DCH + quad * 8;
        #pragma unroll
        for (int kk = 0; kk < 4; ++kk)
            a[kk] = *(const short8*)(xp + kk * 32);
    } else {
        const float* xp = (const float*)x + (size_t)rl * DCH + quad * 8;
        #pragma unroll
        for (int kk = 0; kk < 4; ++kk) {
            float4 f0 = *(const float4*)(xp + kk * 32);
            float4 f1 = *(const float4*)(xp + kk * 32 + 4);
            short8 aa;
            aa[0] = (short)f2bf(f0.x); aa[1] = (short)f2bf(f0.y);
            aa[2] = (short)f2bf(f0.z); aa[3] = (short)f2bf(f0.w);
            aa[4] = (short)f2bf(f1.x); aa[5] = (short)f2bf(f1.y);
            aa[6] = (short)f2bf(f1.z); aa[7] = (short)f2bf(f1.w);
            a[kk] = aa;
        }
    }
    floatx4 acc[8];
    #pragma unroll
    for (int i = 0; i < 8; ++i) acc[i] = (floatx4)(0.f);
    #pragma unroll
    for (int nt = 0; nt < 8; ++nt) {
        #pragma unroll
        for (int kk = 0; kk < 4; ++kk) {
            short8 bfr = *(const short8*)&Wb[(((nt << 2) | kk) * 64 + lane) * 8];
            acc[nt] = __builtin_amdgcn_mfma_f32_16x16x32_bf16(a[kk], bfr, acc[nt], 0, 0, 0);
        }
    }
    #pragma unroll
    for (int i = 0; i < 4; ++i) {
        int row = r0 + quad * 4 + i;
        if (row < N) {
            float dv = dinv[row];
            #pragma unroll
            for (int nt = 0; nt < 8; ++nt)
                y[(size_t)row * DCH + nt * 16 + l16] = f2bf(acc[nt][i] * dv);
        }
    }
}

// gather + BN-stats fused. Half-wave per node (2 nodes/wave), lane owns 4 channels
// (uint2 = 8B loads), 4-deep unrolled edge loop with independent accumulators.
__global__ void gather_stats_kernel(const int* rowptr, const int* col, const u16* y,
                                    const float* dinv, const void* b, const int* ws_i,
                                    float* h, float* sums, float* sumsq, int N) {
    int isbf = ws_i[1];
    int t = threadIdx.x;
    int hw = t >> 5;                 // half-wave id in block [0,8)
    int l32 = t & 31;
    int c0 = l32 * 4;
    float bb[4];
    #pragma unroll
    for (int k = 0; k < 4; ++k) bb[k] = ldf(b, c0 + k, isbf);
    float ps[4] = {0.f, 0.f, 0.f, 0.f}, pq[4] = {0.f, 0.f, 0.f, 0.f};
    int stream_id = blockIdx.x * 8 + hw;
    int nstreams = gridDim.x * 8;
    for (int n = stream_id; n < N; n += nstreams) {
        uint2 qs = *(const uint2*)&y[(size_t)n * DCH + c0];
        float a0[4] = { bf2f((u16)(qs.x & 0xFFFF)), bf2f((u16)(qs.x >> 16)),
                        bf2f((u16)(qs.y & 0xFFFF)), bf2f((u16)(qs.y >> 16)) };
        float a1[4] = {0.f, 0.f, 0.f, 0.f};
        float a2[4] = {0.f, 0.f, 0.f, 0.f};
        float a3[4] = {0.f, 0.f, 0.f, 0.f};
        int beg = rowptr[n], end = rowptr[n + 1];
        int j = beg;
        for (; j + 3 < end; j += 4) {
            int s0 = col[j], s1 = col[j + 1], s2 = col[j + 2], s3 = col[j + 3];
            uint2 q0 = *(const uint2*)&y[(size_t)s0 * DCH + c0];
            uint2 q1 = *(const uint2*)&y[(size_t)s1 * DCH + c0];
            uint2 q2 = *(const uint2*)&y[(size_t)s2 * DCH + c0];
            uint2 q3 = *(const uint2*)&y[(size_t)s3 * DCH + c0];
            a0[0] += bf2f((u16)(q0.x & 0xFFFF)); a0[1] += bf2f((u16)(q0.x >> 16));
            a0[2] += bf2f((u16)(q0.y & 0xFFFF)); a0[3] += bf2f((u16)(q0.y >> 16));
            a1[0] += bf2f((u16)(q1.x & 0xFFFF)); a1[1] += bf2f((u16)(q1.x >> 16));
            a1[2] += bf2f((u16)(q1.y & 0xFFFF)); a1[3] += bf2f((u16)(q1.y >> 16));
            a2[0] += bf2f((u16)(q2.x & 0xFFFF)); a2[1] += bf2f((u16)(q2.x >> 16));
            a2[2] += bf2f((u16)(q2.y & 0xFFFF)); a2[3] += bf2f((u16)(q2.y >> 16));
            a3[0] += bf2f((u16)(q3.x & 0xFFFF)); a3[1] += bf2f((u16)(q3.x >> 16));
            a3[2] += bf2f((u16)(q3.y & 0xFFFF)); a3[3] += bf2f((u16)(q3.y >> 16));
        }
        for (; j < end; ++j) {
            uint2 q0 = *(const uint2*)&y[(size_t)col[j] * DCH + c0];
            a0[0] += bf2f((u16)(q0.x & 0xFFFF)); a0[1] += bf2f((u16)(q0.x >> 16));
            a0[2] += bf2f((u16)(q0.y & 0xFFFF)); a0[3] += bf2f((u16)(q0.y >> 16));
        }
        float dn = dinv[n];
        float4 o;
        o.x = fmaf((a0[0] + a1[0]) + (a2[0] + a3[0]), dn, bb[0]);
        o.y = fmaf((a0[1] + a1[1]) + (a2[1] + a3[1]), dn, bb[1]);
        o.z = fmaf((a0[2] + a1[2]) + (a2[2] + a3[2]), dn, bb[2]);
        o.w = fmaf((a0[3] + a1[3]) + (a2[3] + a3[3]), dn, bb[3]);
        *(float4*)&h[(size_t)n * DCH + c0] = o;
        ps[0] += o.x; pq[0] += o.x * o.x;
        ps[1] += o.y; pq[1] += o.y * o.y;
        ps[2] += o.z; pq[2] += o.z * o.z;
        ps[3] += o.w; pq[3] += o.w * o.w;
    }
    __shared__ float lps[8][DCH], lpq[8][DCH];   // 8 KB
    #pragma unroll
    for (int k = 0; k < 4; ++k) { lps[hw][c0 + k] = ps[k]; lpq[hw][c0 + k] = pq[k]; }
    __syncthreads();
    if (t < DCH) {
        // rotate channel by block to de-synchronize hot-address atomics
        int ch = (t + blockIdx.x * 16) & 127;
        float s = 0.f, q = 0.f;
        #pragma unroll
        for (int i = 0; i < 8; ++i) { s += lps[i][ch]; q += lpq[i][ch]; }
        atomicAdd(&sums[ch], s);
        atomicAdd(&sumsq[ch], q);
    }
}

// ---------- fallback (R5-proven) atomic-path kernels ----------
__global__ void gemm_valu_kernel(const void* x, const void* W, const float* dinv,
                                 const int* ws_i, void* y, int N) {
    __shared__ float WsF[64 * DCH];
    __shared__ float xs[ROWS * DCH];
    int isbf = ws_i[1];
    int t = threadIdx.x;
    int r0 = blockIdx.x * ROWS;
    for (int i = t; i < ROWS * DCH; i += 256) {
        int r = r0 + (i >> 7);
        xs[i] = (r < N) ? ldf(x, r * DCH + (i & 127), isbf) : 0.f;
    }
    int d = t & 127, rh = t >> 7;
    float s[8];
    #pragma unroll
    for (int j = 0; j < 8; ++j) s[j] = 0.f;
    for (int half = 0; half < 2; ++half) {
        __syncthreads();
        for (int i = t; i < 64 * DCH; i += 256)
            WsF[i] = ldf(W, half * 64 * DCH + i, isbf);
        __syncthreads();
        #pragma unroll
        for (int j = 0; j < 8; ++j) {
            int rr = rh + 2 * j;
            float a = s[j];
            #pragma unroll 16
            for (int k = 0; k < 64; ++k)
                a = fmaf(xs[rr * DCH + half * 64 + k], WsF[k * DCH + d], a);
            s[j] = a;
        }
    }
    #pragma unroll
    for (int j = 0; j < 8; ++j) {
        int r = r0 + rh + 2 * j;
        if (r < N) {
            float v = s[j] * dinv[r];
            if (isbf) ((u16*)y)[r * DCH + d] = f2bf(v);
            else      ((float*)y)[r * DCH + d] = v;
        }
    }
}

__global__ void scatter_kernel(const int* ei, int E, const int* ws_i,
                               const void* y, float* acc, int N) {
    int is64 = ws_i[0], isbf = ws_i[1];
    int gid = blockIdx.x * 256 + threadIdx.x;
    int e = gid >> 5;
    if (e >= E) return;
    int c0 = (gid & 31) * 4;
    int s = is64 ? ei[2 * e] : ei[e];
    int d = is64 ? ei[2 * E + 2 * e] : ei[E + e];
    s = min(max(s, 0), N - 1);
    d = min(max(d, 0), N - 1);
    float v0, v1, v2, v3;
    if (isbf) {
        uint2 raw = *(const uint2*)&((const u16*)y)[s * DCH + c0];
        v0 = bf2f((u16)(raw.x & 0xFFFF)); v1 = bf2f((u16)(raw.x >> 16));
        v2 = bf2f((u16)(raw.y & 0xFFFF)); v3 = bf2f((u16)(raw.y >> 16));
    } else {
        float4 raw = *(const float4*)&((const float*)y)[s * DCH + c0];
        v0 = raw.x; v1 = raw.y; v2 = raw.z; v3 = raw.w;
    }
    float* a = &acc[d * DCH + c0];
    atomicAdd(a + 0, v0);
    atomicAdd(a + 1, v1);
    atomicAdd(a + 2, v2);
    atomicAdd(a + 3, v3);
}

__global__ void bnstat_kernel(const void* y, float* acc, const float* dinv,
                              const void* b, int* ws_i,
                              float* sums, float* sumsq, int total) {
    int isbf = ws_i[1];
    int t = threadIdx.x;
    int d = t & 127;
    float bb = ldf(b, d, isbf);
    float ps = 0.f, pq = 0.f;
    int stride = gridDim.x * 256;
    for (int i = blockIdx.x * 256 + t; i < total; i += stride) {
        int r = i >> 7;
        float yv = isbf ? bf2f(((const u16*)y)[i]) : ((const float*)y)[i];
        float v = (yv + acc[i]) * dinv[r] + bb;
        acc[i] = v;
        ps += v;
        pq += v * v;
    }
    __shared__ float ls[256], lq[256];
    ls[t] = ps; lq[t] = pq;
    __syncthreads();
    if (t < 128) {
        atomicAdd(&sums[d], ls[t] + ls[t + 128]);
        atomicAdd(&sumsq[d], lq[t] + lq[t + 128]);
    }
}
// --------------------------------------------------------------

__global__ void out_kernel(const float* h, const void* x,
                           const void* gamma, const void* beta,
                           int* ws_i, const float* sums, const float* sumsq,
                           void* out, int total, float invN) {
    __shared__ float sc[DCH], sh[DCH];
    int isbf = ws_i[1];
    int t = threadIdx.x;
    if (t < DCH) {
        float mean = sums[t] * invN;
        float var = fmaxf(sumsq[t] * invN - mean * mean, 0.f);
        float s = ldf(gamma, t, isbf) * rsqrtf(var + BN_EPS);
        if (!(var < 1e8f && fabsf(s) < 1e6f)) atomicOr(&ws_i[2], 32);
        sc[t] = s;
        sh[t] = ldf(beta, t, isbf) - mean * s;
    }
    __syncthreads();
    int stride = gridDim.x * 256;
    if (isbf) {
        for (int i = blockIdx.x * 256 + t; i < total; i += stride) {
            int d = i & 127;
            float v = fmaf(h[i], sc[d], sh[d]);
            v = fmaxf(v, 0.f) + bf2f(((const u16*)x)[i]);
            ((u16*)out)[i] = f2bf(v);
        }
    } else {
        for (int i = blockIdx.x * 256 + t; i < total; i += stride) {
            int d = i & 127;
            float v = fmaf(h[i], sc[d], sh[d]);
            v = fmaxf(v, 0.f) + ((const float*)x)[i];
            ((float*)out)[i] = v;
        }
    }
}

__global__ void diag_kernel(const int* ws_i, void* out, int n) {
    int e = ws_i[2];
    if (!e) return;
    int isbf = ws_i[1];
    float v = 4096.f + 32.f * (float)(e & 63);
    int stride = gridDim.x * 256;
    if (isbf) {
        u16 code = f2bf(v);
        for (int i = blockIdx.x * 256 + threadIdx.x; i < n; i += stride)
            ((u16*)out)[i] = code;
    } else {
        for (int i = blockIdx.x * 256 + threadIdx.x; i < n; i += stride)
            ((float*)out)[i] = v;
    }
}

extern "C" void kernel_launch(void* const* d_in, const int* in_sizes, int n_in,
                              void* d_out, int out_size, void* d_ws, size_t ws_size,
                              hipStream_t stream) {
    const void* x     = d_in[0];
    const void* W     = d_in[1];
    const void* b     = d_in[2];
    const void* gamma = d_in[3];
    const void* beta  = d_in[4];
    const int*  ei    = (const int*)d_in[5];

    const int N  = in_sizes[0] / DCH;   // 50000
    const int E  = in_sizes[5] / 2;     // 640000
    const int ND = N * DCH;             // 6,400,000
    const int P  = (N + 1023) / 1024;   // scan partials (49)

    char* wsb = (char*)d_ws;
    int*  ws_i = (int*)wsb;

    // layout: ws_i 64B | Wb 32KB | deg[N] | sums[128] | sumsq[128] | rowptr[N+1] | dinv[N] | part[256] | h[ND] | col[E]
    size_t o_wb   = 64;
    size_t o_deg  = o_wb + 32768;
    size_t o_sum  = o_deg + 4 * (size_t)N;
    size_t o_sq   = o_sum + 512;
    size_t o_rp   = o_sq + 512;
    size_t o_dinv = o_rp + 4 * ((size_t)N + 1) + 4;
    size_t o_part = o_dinv + 4 * (size_t)N;
    size_t o_h    = (o_part + 1024 + 255) & ~(size_t)255;
    size_t o_col  = o_h + 4 * (size_t)ND;
    size_t need_csr = o_col + 4 * (size_t)E;

    (void)hipGetLastError();

    if (ws_size >= need_csr) {
        u16*   Wb    = (u16*)(wsb + o_wb);
        int*   deg   = (int*)(wsb + o_deg);
        float* sums  = (float*)(wsb + o_sum);
        float* sumsq = (float*)(wsb + o_sq);
        int*   rowptr= (int*)(wsb + o_rp);
        float* dinv  = (float*)(wsb + o_dinv);
        int*   part  = (int*)(wsb + o_part);
        float* h     = (float*)(wsb + o_h);
        int*   col   = (int*)(wsb + o_col);
        u16*   y     = (u16*)d_out;   // bf16 y in d_out until out_kernel overwrites

        prep_kernel<<<65, 256, 0, stream>>>(ei, 2 * E, (const u16*)x, ws_i,
                                            W, Wb, (float*)(wsb + o_deg), N + 256);
        deg_kernel<<<(E + 255) / 256, 256, 0, stream>>>(ei, E, ws_i, deg, N);
        scanA_kernel<<<P, 256, 0, stream>>>(deg, part, N);
        scanB_kernel<<<1, 256, 0, stream>>>(part, P);
        scanC_kernel<<<P, 256, 0, stream>>>(deg, part, rowptr, dinv, N);
        fillcsr_kernel<<<(E + 255) / 256, 256, 0, stream>>>(ei, E, ws_i, deg, col, N);
        gemm_mfma_kernel<<<(N + 63) / 64, 256, 0, stream>>>(x, Wb, dinv, ws_i, y, N);
        gather_stats_kernel<<<1024, 256, 0, stream>>>(rowptr, col, y, dinv, b, ws_i,
                                                      h, sums, sumsq, N);
        out_kernel<<<1024, 256, 0, stream>>>(h, x, gamma, beta, ws_i, sums, sumsq,
                                             d_out, ND, 1.0f / (float)N);
        diag_kernel<<<512, 256, 0, stream>>>(ws_i, d_out, out_size);
    } else {
        // R5-proven fallback: ws_i | deg | dinv | sums | sumsq | acc
        int*   deg   = (int*)(wsb + 16);
        float* dinv  = (float*)(wsb + 16 + 4 * (size_t)N);
        float* sums  = (float*)(wsb + 16 + 8 * (size_t)N);
        float* sumsq = sums + DCH;
        float* acc   = sumsq + DCH;
        size_t need = 16 + 8 * (size_t)N + 1024 + 4 * (size_t)ND;
        if (ws_size < need) {
            int mb = (int)(ws_size >> 20); if (mb > 127) mb = 127;
            float v = 2048.f + 16.f * (float)mb;
            unsigned u; __builtin_memcpy(&u, &v, 4);
            paint_kernel<<<1024, 256, 0, stream>>>((u16*)d_out, out_size, u >> 16);
            return;
        }
        detect_kernel<<<1, 256, 0, stream>>>(ei, 2 * E, (const u16*)x, ws_i);
        zero_kernel<<<2048, 256, 0, stream>>>((float*)(wsb + 16), 2 * N + 256 + ND);
        deg_kernel<<<(E + 255) / 256, 256, 0, stream>>>(ei, E, ws_i, deg, N);
        dinv_kernel<<<(N + 255) / 256, 256, 0, stream>>>(deg, dinv, N, ws_i);
        gemm_valu_kernel<<<(N + ROWS - 1) / ROWS, 256, 0, stream>>>(x, W, dinv, ws_i, d_out, N);
        scatter_kernel<<<(E * 32 + 255) / 256, 256, 0, stream>>>(ei, E, ws_i, d_out, acc, N);
        bnstat_kernel<<<240, 256, 0, stream>>>(d_out, acc, dinv, b, ws_i, sums, sumsq, ND);
        out_kernel<<<256, 256, 0, stream>>>(acc, x, gamma, beta, ws_i, sums, sumsq,
                                            d_out, ND, 1.0f / (float)N);
        diag_kernel<<<512, 256, 0, stream>>>(ws_i, d_out, out_size);
    }

    if (hipGetLastError() != hipSuccess)
        hipMemsetAsync(d_out, 0x42, (size_t)out_size * 2, stream);
}